// Round 1
// baseline (501.955 us; speedup 1.0000x reference)
//
#include <hip/hip_runtime.h>
#include <hip/hip_bf16.h>

#define B_ 4
#define C_ 512
#define L_ 2048
#define H_ 8
#define E_ 64
#define SCALE 0.125f
#define L2E 1.44269504088896f
#define NEG_BIG -3.0e38f
#define SENT -1.0e30f

typedef __attribute__((ext_vector_type(8))) short bf16x8;
typedef __attribute__((ext_vector_type(4))) float f32x4;

static __device__ __forceinline__ unsigned short f2bf(float f) {
    union { float f; unsigned u; } v; v.f = f;
    unsigned r = v.u + 0x7FFFu + ((v.u >> 16) & 1u);
    return (unsigned short)(r >> 16);
}

// ---------------- Pass A: cast x (B,C,L) fp32 -> bf16 ----------------
__global__ __launch_bounds__(256) void cast_kernel(const float* __restrict__ x,
                                                   unsigned short* __restrict__ xb, int n4) {
    int i = blockIdx.x * blockDim.x + threadIdx.x;
    if (i >= n4) return;
    float4 v = reinterpret_cast<const float4*>(x)[i];
    union { unsigned short u[4]; unsigned long long ll; } o;
    o.u[0] = f2bf(v.x); o.u[1] = f2bf(v.y); o.u[2] = f2bf(v.z); o.u[3] = f2bf(v.w);
    reinterpret_cast<unsigned long long*>(xb)[i] = o.ll;
}

// ---------------- Pass B: Q = W_q @ x + b_q, stored bf16 [(b*H+h), l, e] ----------------
__global__ __launch_bounds__(256) void proj_kernel(const float* __restrict__ W,
                                                   const float* __restrict__ bq,
                                                   const unsigned short* __restrict__ xb,
                                                   unsigned short* __restrict__ qb) {
    const int lt = blockIdx.x;          // l-tile (64)
    const int h  = blockIdx.y;          // o-tile == head
    const int b  = blockIdx.z;
    const int tid = threadIdx.x;
    const int w = tid >> 6, lane = tid & 63;
    const int lr = lane & 15, lg = lane >> 4;
    const int l0 = lt * 64 + w * 16;
    const int o0 = h * 64;

    f32x4 acc[4] = {};
    const float* Wp = W + (size_t)(o0 + lr) * C_ + lg * 8;
    const unsigned short* xp = xb + ((size_t)b * C_ + lg * 8) * L_ + l0 + lr;

    for (int ks = 0; ks < 16; ++ks) {
        const int k0 = ks * 32;
        bf16x8 bf;
        #pragma unroll
        for (int j = 0; j < 8; ++j) bf[j] = (short)xp[(size_t)(k0 + j) * L_];
        #pragma unroll
        for (int mt = 0; mt < 4; ++mt) {
            const float* ap = Wp + (size_t)mt * 16 * C_ + k0;
            bf16x8 af;
            #pragma unroll
            for (int j = 0; j < 8; ++j) af[j] = (short)f2bf(ap[j]);
            acc[mt] = __builtin_amdgcn_mfma_f32_16x16x32_bf16(af, bf, acc[mt], 0, 0, 0);
        }
    }
    const int l = l0 + lr;
    const int bh = b * H_ + h;
    unsigned short* qrow = qb + ((size_t)bh * L_ + l) * 64;
    #pragma unroll
    for (int mt = 0; mt < 4; ++mt) {
        const int e0 = mt * 16 + lg * 4;
        const float4 bb = *reinterpret_cast<const float4*>(bq + o0 + e0);
        union { unsigned short u[4]; unsigned long long ll; } o;
        o.u[0] = f2bf(acc[mt][0] + bb.x);
        o.u[1] = f2bf(acc[mt][1] + bb.y);
        o.u[2] = f2bf(acc[mt][2] + bb.z);
        o.u[3] = f2bf(acc[mt][3] + bb.w);
        *reinterpret_cast<unsigned long long*>(qrow + e0) = o.ll;
    }
}

// ---------------- Pass C: softmax stats (m, 1/l) per row ----------------
__global__ __launch_bounds__(256) void stats_kernel(const unsigned short* __restrict__ qb,
                                                    float* __restrict__ mArr,
                                                    float* __restrict__ liArr) {
    const int qt = blockIdx.x, h = blockIdx.y, b = blockIdx.z;
    const int tid = threadIdx.x, w = tid >> 6, lane = tid & 63;
    const int lr = lane & 15, lg = lane >> 4;
    const int q0 = qt * 64;
    const int bh = b * H_ + h;
    const unsigned short* Qbase = qb + (size_t)bh * L_ * 64;

    bf16x8 a[4][2];
    #pragma unroll
    for (int mt = 0; mt < 4; ++mt)
        #pragma unroll
        for (int es = 0; es < 2; ++es)
            a[mt][es] = *reinterpret_cast<const bf16x8*>(Qbase + (q0 + mt * 16 + lr) * 64 + es * 32 + lg * 8);

    float runm[16], runl[16];
    #pragma unroll
    for (int i = 0; i < 16; ++i) { runm[i] = SENT; runl[i] = 0.f; }

    const int nct = (q0 >> 6) + 1;
    for (int ct = w; ct < nct; ct += 4) {
        const int k0 = ct * 64;
        bf16x8 bk[4][2];
        #pragma unroll
        for (int nt = 0; nt < 4; ++nt)
            #pragma unroll
            for (int es = 0; es < 2; ++es)
                bk[nt][es] = *reinterpret_cast<const bf16x8*>(Qbase + (k0 + nt * 16 + lr) * 64 + es * 32 + lg * 8);
        #pragma unroll
        for (int mt = 0; mt < 4; ++mt) {
            f32x4 s[4];
            #pragma unroll
            for (int nt = 0; nt < 4; ++nt) {
                f32x4 z = {};
                z = __builtin_amdgcn_mfma_f32_16x16x32_bf16(a[mt][0], bk[nt][0], z, 0, 0, 0);
                z = __builtin_amdgcn_mfma_f32_16x16x32_bf16(a[mt][1], bk[nt][1], z, 0, 0, 0);
                s[nt] = z;
            }
            #pragma unroll
            for (int r = 0; r < 4; ++r) {
                const int q = q0 + mt * 16 + lg * 4 + r;
                float sv[4];
                #pragma unroll
                for (int nt = 0; nt < 4; ++nt) {
                    const int k = k0 + nt * 16 + lr;
                    sv[nt] = (k <= q) ? s[nt][r] * SCALE : NEG_BIG;
                }
                const float cmax = fmaxf(fmaxf(sv[0], sv[1]), fmaxf(sv[2], sv[3]));
                const int idx = mt * 4 + r;
                const float mo = runm[idx];
                const float mn = fmaxf(mo, cmax);
                float sum = 0.f;
                #pragma unroll
                for (int nt = 0; nt < 4; ++nt) sum += exp2f((sv[nt] - mn) * L2E);
                runl[idx] = runl[idx] * exp2f((mo - mn) * L2E) + sum;
                runm[idx] = mn;
            }
        }
    }

    // intra-wave merge across the 16 lanes holding different k-columns
    #pragma unroll
    for (int i = 0; i < 16; ++i) {
        float m = runm[i], l = runl[i];
        #pragma unroll
        for (int d = 1; d < 16; d <<= 1) {
            const float mo = __shfl_xor(m, d);
            const float lo = __shfl_xor(l, d);
            const float mn = fmaxf(m, mo);
            l = l * exp2f((m - mn) * L2E) + lo * exp2f((mo - mn) * L2E);
            m = mn;
        }
        runm[i] = m; runl[i] = l;
    }

    __shared__ float sm[4][64], sl[4][64];
    if (lr == 0) {
        #pragma unroll
        for (int mt = 0; mt < 4; ++mt)
            #pragma unroll
            for (int r = 0; r < 4; ++r) {
                const int row = mt * 16 + lg * 4 + r;
                sm[w][row] = runm[mt * 4 + r];
                sl[w][row] = runl[mt * 4 + r];
            }
    }
    __syncthreads();
    if (tid < 64) {
        float m = sm[0][tid], l = sl[0][tid];
        #pragma unroll
        for (int ww = 1; ww < 4; ++ww) {
            const float mo = sm[ww][tid], lo = sl[ww][tid];
            const float mn = fmaxf(m, mo);
            l = l * exp2f((m - mn) * L2E) + lo * exp2f((mo - mn) * L2E);
            m = mn;
        }
        mArr[bh * L_ + q0 + tid] = m;
        liArr[bh * L_ + q0 + tid] = 1.0f / l;
    }
}

// ---------------- Pass D: P·V + residual + transposed write ----------------
__global__ __launch_bounds__(512) void pv_kernel(const unsigned short* __restrict__ qb,
                                                 const unsigned short* __restrict__ xb,
                                                 const float* __restrict__ x,
                                                 const float* __restrict__ mArr,
                                                 const float* __restrict__ liArr,
                                                 float* __restrict__ out) {
    const int qt = blockIdx.x, h = blockIdx.y, b = blockIdx.z;
    const int tid = threadIdx.x, w = tid >> 6, lane = tid & 63;
    const int lr = lane & 15, lg = lane >> 4;
    const int q0 = qt * 64;
    const int bh = b * H_ + h;
    const unsigned short* Qbase = qb + (size_t)bh * L_ * 64;

    __shared__ unsigned short P[64 * 128];   // XOR-swizzled: granule g' = g ^ (row&15)

    bf16x8 a[4][2];
    #pragma unroll
    for (int mt = 0; mt < 4; ++mt)
        #pragma unroll
        for (int es = 0; es < 2; ++es)
            a[mt][es] = *reinterpret_cast<const bf16x8*>(Qbase + (q0 + mt * 16 + lr) * 64 + es * 32 + lg * 8);

    float mrow[16];
    #pragma unroll
    for (int mt = 0; mt < 4; ++mt) {
        const f32x4 mv = *reinterpret_cast<const f32x4*>(mArr + bh * L_ + q0 + mt * 16 + lg * 4);
        #pragma unroll
        for (int r = 0; r < 4; ++r) mrow[mt * 4 + r] = mv[r];
    }

    f32x4 acc[4][4] = {};
    const int nkt = (q0 >> 7) + 1;
    const unsigned short* Vbase = xb + (size_t)b * C_ * L_;

    for (int kt = 0; kt < nkt; ++kt) {
        const int k0 = kt * 128;
        // ---- S phase: wave w computes P columns [k0+w*16, k0+w*16+16) ----
        bf16x8 bk[2];
        #pragma unroll
        for (int es = 0; es < 2; ++es)
            bk[es] = *reinterpret_cast<const bf16x8*>(Qbase + (k0 + w * 16 + lr) * 64 + es * 32 + lg * 8);
        __syncthreads();   // prev-iter PV reads done before overwriting P
        const int kcol = k0 + w * 16 + lr;
        #pragma unroll
        for (int mt = 0; mt < 4; ++mt) {
            f32x4 z = {};
            z = __builtin_amdgcn_mfma_f32_16x16x32_bf16(a[mt][0], bk[0], z, 0, 0, 0);
            z = __builtin_amdgcn_mfma_f32_16x16x32_bf16(a[mt][1], bk[1], z, 0, 0, 0);
            #pragma unroll
            for (int r = 0; r < 4; ++r) {
                const int q = q0 + mt * 16 + lg * 4 + r;
                const float sv = (kcol <= q) ? z[r] * SCALE : NEG_BIG;
                const float p = exp2f((sv - mrow[mt * 4 + r]) * L2E);
                const int row = mt * 16 + lg * 4 + r;
                const int cl = w * 16 + lr;
                const int g = cl >> 3;
                P[row * 128 + ((g ^ (row & 15)) << 3) + (cl & 7)] = f2bf(p);
            }
        }
        __syncthreads();
        // ---- PV phase: wave w owns channels [w*64, w*64+64) ----
        #pragma unroll
        for (int ks = 0; ks < 4; ++ks) {
            bf16x8 pa[4], pv[4];
            #pragma unroll
            for (int mt = 0; mt < 4; ++mt) {
                const int row = mt * 16 + lr;
                const int g = ks * 4 + lg;
                pa[mt] = *reinterpret_cast<const bf16x8*>(&P[row * 128 + ((g ^ (row & 15)) << 3)]);
            }
            #pragma unroll
            for (int nt = 0; nt < 4; ++nt) {
                const int c = w * 64 + nt * 16 + lr;
                pv[nt] = *reinterpret_cast<const bf16x8*>(Vbase + (size_t)c * L_ + k0 + ks * 32 + lg * 8);
            }
            #pragma unroll
            for (int mt = 0; mt < 4; ++mt)
                #pragma unroll
                for (int nt = 0; nt < 4; ++nt)
                    acc[mt][nt] = __builtin_amdgcn_mfma_f32_16x16x32_bf16(pa[mt], pv[nt], acc[mt][nt], 0, 0, 0);
        }
    }

    // ---- epilogue: scale by 1/l, add residual, write out[b, h*C+c, l] ----
    const float* xres = x + (size_t)b * C_ * L_;
    float* ob = out + ((size_t)(b * H_ + h)) * C_ * L_;
    #pragma unroll
    for (int mt = 0; mt < 4; ++mt) {
        const f32x4 li = *reinterpret_cast<const f32x4*>(liArr + bh * L_ + q0 + mt * 16 + lg * 4);
        const int lbase = q0 + mt * 16 + lg * 4;
        #pragma unroll
        for (int nt = 0; nt < 4; ++nt) {
            const int c = w * 64 + nt * 16 + lr;
            const f32x4 res = *reinterpret_cast<const f32x4*>(xres + (size_t)c * L_ + lbase);
            f32x4 o;
            #pragma unroll
            for (int r = 0; r < 4; ++r) o[r] = acc[mt][nt][r] * li[r] + res[r];
            *reinterpret_cast<f32x4*>(ob + (size_t)c * L_ + lbase) = o;
        }
    }
}

extern "C" void kernel_launch(void* const* d_in, const int* in_sizes, int n_in,
                              void* d_out, int out_size, void* d_ws, size_t ws_size,
                              hipStream_t stream) {
    const float* x  = (const float*)d_in[0];
    const float* Wq = (const float*)d_in[1];
    const float* bq = (const float*)d_in[2];
    float* out = (float*)d_out;

    unsigned short* xb   = (unsigned short*)d_ws;                       // B*C*L bf16 = 8 MiB
    unsigned short* qbuf = xb + (size_t)B_ * C_ * L_;                   // B*H*L*E bf16 = 8 MiB
    float* mArr  = (float*)(qbuf + (size_t)B_ * H_ * L_ * E_);          // 256 KiB
    float* liArr = mArr + (size_t)B_ * H_ * L_;                         // 256 KiB

    const int n4 = (B_ * C_ * L_) / 4;
    cast_kernel<<<(n4 + 255) / 256, 256, 0, stream>>>(x, xb, n4);
    proj_kernel<<<dim3(32, 8, 4), 256, 0, stream>>>(Wq, bq, xb, qbuf);
    stats_kernel<<<dim3(32, 8, 4), 256, 0, stream>>>(qbuf, mArr, liArr);
    pv_kernel<<<dim3(32, 8, 4), 512, 0, stream>>>(qbuf, xb, x, mArr, liArr, out);
}

// Round 2
// 357.470 us; speedup vs baseline: 1.4042x; 1.4042x over previous
//
#include <hip/hip_runtime.h>
#include <hip/hip_bf16.h>

#define B_ 4
#define C_ 512
#define L_ 2048
#define H_ 8
#define E_ 64
// sqrt(0.125 * log2(e)) — folded into Q so QK^T directly yields log2-domain scores
#define QSCALE 0.4246609f

typedef __attribute__((ext_vector_type(8))) short bf16x8;
typedef __attribute__((ext_vector_type(4))) float f32x4;

static __device__ __forceinline__ unsigned short f2bf(float f) {
    union { float f; unsigned u; } v; v.f = f;
    unsigned r = v.u + 0x7FFFu + ((v.u >> 16) & 1u);
    return (unsigned short)(r >> 16);
}

// ---------------- Pass A: cast x -> xb (bf16, [b][c][l]) and xt (bf16, [b][l][c]) ----------------
__global__ __launch_bounds__(256) void prep_kernel(const float* __restrict__ x,
                                                   unsigned short* __restrict__ xb,
                                                   unsigned short* __restrict__ xt) {
    const int lt = blockIdx.x, ct = blockIdx.y, b = blockIdx.z;
    const int l0 = lt * 64, c0 = ct * 64;
    const int t = threadIdx.x;
    __shared__ unsigned short T[64 * 72];   // [c][l], padded row to 72 elems (144B, 16B-aligned)

    const int cl = t >> 2, lo = (t & 3) * 16;
    const float* src = x + ((size_t)(b * C_ + c0 + cl)) * L_ + l0 + lo;
    unsigned short u[16];
    #pragma unroll
    for (int j = 0; j < 16; j += 4) {
        float4 v = *reinterpret_cast<const float4*>(src + j);
        u[j] = f2bf(v.x); u[j + 1] = f2bf(v.y); u[j + 2] = f2bf(v.z); u[j + 3] = f2bf(v.w);
    }
    unsigned short* xbp = xb + ((size_t)(b * C_ + c0 + cl)) * L_ + l0 + lo;
    reinterpret_cast<uint4*>(xbp)[0] = reinterpret_cast<uint4*>(u)[0];
    reinterpret_cast<uint4*>(xbp)[1] = reinterpret_cast<uint4*>(u)[1];
    reinterpret_cast<uint4*>(&T[cl * 72 + lo])[0] = reinterpret_cast<uint4*>(u)[0];
    reinterpret_cast<uint4*>(&T[cl * 72 + lo + 8])[0] = reinterpret_cast<uint4*>(u)[1];
    __syncthreads();
    const int ll = t >> 2, co = (t & 3) * 16;
    unsigned short v16[16];
    #pragma unroll
    for (int j = 0; j < 16; ++j) v16[j] = T[(co + j) * 72 + ll];
    unsigned short* xtp = xt + ((size_t)b * L_ + l0 + ll) * C_ + c0 + co;
    reinterpret_cast<uint4*>(xtp)[0] = reinterpret_cast<uint4*>(v16)[0];
    reinterpret_cast<uint4*>(xtp)[1] = reinterpret_cast<uint4*>(v16)[1];
}

// ---------------- Pass A2: cast W fp32 -> bf16 ----------------
__global__ __launch_bounds__(256) void wcast_kernel(const float* __restrict__ W,
                                                    unsigned short* __restrict__ Wb) {
    const int i = blockIdx.x * 256 + threadIdx.x;   // 65536 threads x 4 elems
    float4 v = reinterpret_cast<const float4*>(W)[i];
    union { unsigned short u[4]; unsigned long long ll; } o;
    o.u[0] = f2bf(v.x); o.u[1] = f2bf(v.y); o.u[2] = f2bf(v.z); o.u[3] = f2bf(v.w);
    reinterpret_cast<unsigned long long*>(Wb)[i] = o.ll;
}

// ---------------- Pass B: Q = (W x + b) * QSCALE, bf16 [(b*H+h)][l][e] ----------------
__global__ __launch_bounds__(256) void proj_kernel(const unsigned short* __restrict__ Wb,
                                                   const float* __restrict__ bq,
                                                   const unsigned short* __restrict__ xt,
                                                   unsigned short* __restrict__ qb) {
    const int lt = blockIdx.x, h = blockIdx.y, b = blockIdx.z;
    const int tid = threadIdx.x, w = tid >> 6, lane = tid & 63;
    const int lr = lane & 15, lg = lane >> 4;
    const int l = lt * 64 + w * 16 + lr;
    const int o0 = h * 64;

    f32x4 acc[4] = {};
    const unsigned short* xrow = xt + ((size_t)b * L_ + l) * C_;
    for (int ks = 0; ks < 16; ++ks) {
        bf16x8 bf = *reinterpret_cast<const bf16x8*>(xrow + ks * 32 + lg * 8);
        #pragma unroll
        for (int mt = 0; mt < 4; ++mt) {
            bf16x8 af = *reinterpret_cast<const bf16x8*>(Wb + (size_t)(o0 + mt * 16 + lr) * C_ + ks * 32 + lg * 8);
            acc[mt] = __builtin_amdgcn_mfma_f32_16x16x32_bf16(af, bf, acc[mt], 0, 0, 0);
        }
    }
    const int bh = b * H_ + h;
    unsigned short* qrow = qb + ((size_t)bh * L_ + l) * 64;
    #pragma unroll
    for (int mt = 0; mt < 4; ++mt) {
        const int e0 = mt * 16 + lg * 4;
        const float4 bb = *reinterpret_cast<const float4*>(bq + o0 + e0);
        union { unsigned short u[4]; unsigned long long ll; } o;
        o.u[0] = f2bf((acc[mt][0] + bb.x) * QSCALE);
        o.u[1] = f2bf((acc[mt][1] + bb.y) * QSCALE);
        o.u[2] = f2bf((acc[mt][2] + bb.z) * QSCALE);
        o.u[3] = f2bf((acc[mt][3] + bb.w) * QSCALE);
        *reinterpret_cast<unsigned long long*>(qrow + e0) = o.ll;
    }
}

// ---------------- Pass C: fused S/softmax-sum/PV + residual + transposed write ----------------
__global__ __launch_bounds__(512, 4) void pv_kernel(const unsigned short* __restrict__ qb,
                                                    const unsigned short* __restrict__ xb,
                                                    const float* __restrict__ x,
                                                    float* __restrict__ out) {
    const int qt = 31 - blockIdx.x;          // heavy tiles first
    const int h = blockIdx.y, b = blockIdx.z;
    const int tid = threadIdx.x, w = tid >> 6, lane = tid & 63;
    const int lr = lane & 15, lg = lane >> 4;
    const int q0 = qt * 64, bh = b * H_ + h;
    const int qlim = q0 + 63;
    const unsigned short* Qbase = qb + (size_t)bh * L_ * 64;

    __shared__ unsigned short Qt[64 * 64];       // swizzled Q tile
    __shared__ unsigned short P2[2][64 * 128];   // double-buffered P, XOR-swizzled
    __shared__ float rsT[64][8];                 // per-wave rowsum partials

    // stage Q tile into LDS (granule g -> g ^ (row&7))
    {
        const int r = tid >> 3, g = tid & 7;
        bf16x8 v = *reinterpret_cast<const bf16x8*>(Qbase + (size_t)(q0 + r) * 64 + g * 8);
        *reinterpret_cast<bf16x8*>(&Qt[r * 64 + ((g ^ (r & 7)) << 3)]) = v;
    }

    f32x4 acc[4][4] = {};
    float rs[4] = {0.f, 0.f, 0.f, 0.f};
    const int nkt = (q0 >> 7) + 1;
    const unsigned short* Vbase = xb + (size_t)b * C_ * L_;

    // prefetch K fragments for tile 0 (K == Q)
    bf16x8 kb0 = *reinterpret_cast<const bf16x8*>(Qbase + (size_t)(w * 16 + lr) * 64 + lg * 8);
    bf16x8 kb1 = *reinterpret_cast<const bf16x8*>(Qbase + (size_t)(w * 16 + lr) * 64 + 32 + lg * 8);

    __syncthreads();   // Qt ready

    for (int kt = 0; kt < nkt; ++kt) {
        const int k0 = kt * 128;
        const bool active = (k0 + (w & ~1) * 16) <= qlim;   // this wave's ks-block is read by PV
        unsigned short* Pb = (unsigned short*)P2[kt & 1];

        if (active) {
            // S phase: z[nt] = K-slab x Q  -> D[k][q], 4 consecutive k per lane
            f32x4 z[4];
            #pragma unroll
            for (int nt = 0; nt < 4; ++nt) {
                bf16x8 aq0 = *reinterpret_cast<const bf16x8*>(&Qt[(nt * 16 + lr) * 64 + ((lg ^ (lr & 7)) << 3)]);
                bf16x8 aq1 = *reinterpret_cast<const bf16x8*>(&Qt[(nt * 16 + lr) * 64 + (((4 + lg) ^ (lr & 7)) << 3)]);
                f32x4 zz = {};
                zz = __builtin_amdgcn_mfma_f32_16x16x32_bf16(kb0, aq0, zz, 0, 0, 0);
                zz = __builtin_amdgcn_mfma_f32_16x16x32_bf16(kb1, aq1, zz, 0, 0, 0);
                z[nt] = zz;
            }
            // prefetch next K slab during the VALU tail
            if (kt + 1 < nkt) {
                const size_t krow = (size_t)(k0 + 128 + w * 16 + lr) * 64;
                kb0 = *reinterpret_cast<const bf16x8*>(Qbase + krow + lg * 8);
                kb1 = *reinterpret_cast<const bf16x8*>(Qbase + krow + 32 + lg * 8);
            }
            const int kbase = k0 + w * 16 + lg * 4;
            #pragma unroll
            for (int nt = 0; nt < 4; ++nt) {
                const int q = q0 + nt * 16 + lr;
                const float p0 = (kbase + 0 <= q) ? exp2f(z[nt][0]) : 0.f;
                const float p1 = (kbase + 1 <= q) ? exp2f(z[nt][1]) : 0.f;
                const float p2 = (kbase + 2 <= q) ? exp2f(z[nt][2]) : 0.f;
                const float p3 = (kbase + 3 <= q) ? exp2f(z[nt][3]) : 0.f;
                float sum = (p0 + p1) + (p2 + p3);
                sum += __shfl_xor(sum, 16);
                sum += __shfl_xor(sum, 32);
                rs[nt] += sum;
                unsigned r01, r23;
                asm("v_cvt_pk_bf16_f32 %0, %1, %2" : "=v"(r01) : "v"(p0), "v"(p1));
                asm("v_cvt_pk_bf16_f32 %0, %1, %2" : "=v"(r23) : "v"(p2), "v"(p3));
                const int row = nt * 16 + lr;
                const int col = w * 16 + lg * 4;
                const int gg = (col >> 3) ^ lr;
                const unsigned long long pk = ((unsigned long long)r23 << 32) | r01;
                *reinterpret_cast<unsigned long long*>(&Pb[row * 128 + (gg << 3) + (col & 7)]) = pk;
            }
        } else if (kt + 1 < nkt) {
            const size_t krow = (size_t)(k0 + 128 + w * 16 + lr) * 64;
            kb0 = *reinterpret_cast<const bf16x8*>(Qbase + krow + lg * 8);
            kb1 = *reinterpret_cast<const bf16x8*>(Qbase + krow + 32 + lg * 8);
        }
        __syncthreads();
        // PV phase: wave owns channels [w*64, w*64+64)
        const int ksmax = min(4, ((qlim - k0) >> 5) + 1);
        for (int ks = 0; ks < ksmax; ++ks) {
            bf16x8 pvv[4];
            #pragma unroll
            for (int ct = 0; ct < 4; ++ct) {
                const int c = w * 64 + ct * 16 + lr;
                pvv[ct] = *reinterpret_cast<const bf16x8*>(Vbase + (size_t)c * L_ + k0 + ks * 32 + lg * 8);
            }
            bf16x8 pa[4];
            #pragma unroll
            for (int mt = 0; mt < 4; ++mt) {
                const int row = mt * 16 + lr;
                const int g2 = (ks * 4 + lg) ^ lr;
                pa[mt] = *reinterpret_cast<const bf16x8*>(&Pb[row * 128 + (g2 << 3)]);
            }
            __builtin_amdgcn_s_setprio(1);
            #pragma unroll
            for (int mt = 0; mt < 4; ++mt)
                #pragma unroll
                for (int ct = 0; ct < 4; ++ct)
                    acc[mt][ct] = __builtin_amdgcn_mfma_f32_16x16x32_bf16(pa[mt], pvv[ct], acc[mt][ct], 0, 0, 0);
            __builtin_amdgcn_s_setprio(0);
        }
    }

    // merge per-wave rowsums
    if (lg == 0) {
        #pragma unroll
        for (int nt = 0; nt < 4; ++nt) rsT[nt * 16 + lr][w] = rs[nt];
    }
    __syncthreads();
    float li[16];
    #pragma unroll
    for (int mt = 0; mt < 4; ++mt)
        #pragma unroll
        for (int r = 0; r < 4; ++r) {
            const int row = mt * 16 + lg * 4 + r;
            const f32x4 s0 = *reinterpret_cast<const f32x4*>(&rsT[row][0]);
            const f32x4 s1 = *reinterpret_cast<const f32x4*>(&rsT[row][4]);
            li[mt * 4 + r] = 1.f / (((s0[0] + s0[1]) + (s0[2] + s0[3])) + ((s1[0] + s1[1]) + (s1[2] + s1[3])));
        }

    const float* xres = x + (size_t)b * C_ * L_;
    float* ob = out + (size_t)bh * C_ * L_;
    #pragma unroll
    for (int mt = 0; mt < 4; ++mt) {
        const int lbase = q0 + mt * 16 + lg * 4;
        #pragma unroll
        for (int ct = 0; ct < 4; ++ct) {
            const int c = w * 64 + ct * 16 + lr;
            const f32x4 res = *reinterpret_cast<const f32x4*>(xres + (size_t)c * L_ + lbase);
            f32x4 o;
            #pragma unroll
            for (int r = 0; r < 4; ++r) o[r] = acc[mt][ct][r] * li[mt * 4 + r] + res[r];
            *reinterpret_cast<f32x4*>(ob + (size_t)c * L_ + lbase) = o;
        }
    }
}

extern "C" void kernel_launch(void* const* d_in, const int* in_sizes, int n_in,
                              void* d_out, int out_size, void* d_ws, size_t ws_size,
                              hipStream_t stream) {
    const float* x  = (const float*)d_in[0];
    const float* Wq = (const float*)d_in[1];
    const float* bq = (const float*)d_in[2];
    float* out = (float*)d_out;

    unsigned short* xb   = (unsigned short*)d_ws;                        // B*C*L bf16   = 8 MiB
    unsigned short* xt   = xb + (size_t)B_ * C_ * L_;                    // B*L*C bf16   = 8 MiB
    unsigned short* qbuf = xt + (size_t)B_ * L_ * C_;                    // B*H*L*E bf16 = 8 MiB
    unsigned short* Wb   = qbuf + (size_t)B_ * H_ * L_ * E_;             // 512 KiB

    prep_kernel<<<dim3(32, 8, 4), 256, 0, stream>>>(x, xb, xt);
    wcast_kernel<<<dim3(256), 256, 0, stream>>>(Wq, Wb);
    proj_kernel<<<dim3(32, 8, 4), 256, 0, stream>>>(Wb, bq, xt, qbuf);
    pv_kernel<<<dim3(32, 8, 4), 512, 0, stream>>>(qbuf, xb, x, out);
}

// Round 3
// 342.293 us; speedup vs baseline: 1.4665x; 1.0443x over previous
//
#include <hip/hip_runtime.h>
#include <hip/hip_bf16.h>

#define B_ 4
#define C_ 512
#define L_ 2048
#define H_ 8
#define E_ 64
// sqrt(0.125 * log2(e)) — folded into Q (and K=Q) so QK^T yields log2-domain scores
#define QSCALE 0.4246609f

typedef __attribute__((ext_vector_type(8))) short bf16x8;
typedef __attribute__((ext_vector_type(4))) float f32x4;

static __device__ __forceinline__ unsigned short f2bf(float f) {
    union { float f; unsigned u; } v; v.f = f;
    unsigned r = v.u + 0x7FFFu + ((v.u >> 16) & 1u);
    return (unsigned short)(r >> 16);
}

// ---------------- Pass A: cast x -> xb (bf16, [b][c][l]) and xt (bf16, [b][l][c]) ----------------
__global__ __launch_bounds__(256) void prep_kernel(const float* __restrict__ x,
                                                   unsigned short* __restrict__ xb,
                                                   unsigned short* __restrict__ xt) {
    const int lt = blockIdx.x, ct = blockIdx.y, b = blockIdx.z;
    const int l0 = lt * 64, c0 = ct * 64;
    const int t = threadIdx.x;
    __shared__ unsigned short T[64 * 72];

    const int cl = t >> 2, lo = (t & 3) * 16;
    const float* src = x + ((size_t)(b * C_ + c0 + cl)) * L_ + l0 + lo;
    unsigned short u[16];
    #pragma unroll
    for (int j = 0; j < 16; j += 4) {
        float4 v = *reinterpret_cast<const float4*>(src + j);
        u[j] = f2bf(v.x); u[j + 1] = f2bf(v.y); u[j + 2] = f2bf(v.z); u[j + 3] = f2bf(v.w);
    }
    unsigned short* xbp = xb + ((size_t)(b * C_ + c0 + cl)) * L_ + l0 + lo;
    reinterpret_cast<uint4*>(xbp)[0] = reinterpret_cast<uint4*>(u)[0];
    reinterpret_cast<uint4*>(xbp)[1] = reinterpret_cast<uint4*>(u)[1];
    reinterpret_cast<uint4*>(&T[cl * 72 + lo])[0] = reinterpret_cast<uint4*>(u)[0];
    reinterpret_cast<uint4*>(&T[cl * 72 + lo + 8])[0] = reinterpret_cast<uint4*>(u)[1];
    __syncthreads();
    const int ll = t >> 2, co = (t & 3) * 16;
    unsigned short v16[16];
    #pragma unroll
    for (int j = 0; j < 16; ++j) v16[j] = T[(co + j) * 72 + ll];
    unsigned short* xtp = xt + ((size_t)b * L_ + l0 + ll) * C_ + c0 + co;
    reinterpret_cast<uint4*>(xtp)[0] = reinterpret_cast<uint4*>(v16)[0];
    reinterpret_cast<uint4*>(xtp)[1] = reinterpret_cast<uint4*>(v16)[1];
}

// ---------------- Pass A2: cast W fp32 -> bf16 ----------------
__global__ __launch_bounds__(256) void wcast_kernel(const float* __restrict__ W,
                                                    unsigned short* __restrict__ Wb) {
    const int i = blockIdx.x * 256 + threadIdx.x;
    float4 v = reinterpret_cast<const float4*>(W)[i];
    union { unsigned short u[4]; unsigned long long ll; } o;
    o.u[0] = f2bf(v.x); o.u[1] = f2bf(v.y); o.u[2] = f2bf(v.z); o.u[3] = f2bf(v.w);
    reinterpret_cast<unsigned long long*>(Wb)[i] = o.ll;
}

// ---------------- Pass B: Q = (W x + b) * QSCALE, bf16 [(b*H+h)][l][e] ----------------
__global__ __launch_bounds__(256) void proj_kernel(const unsigned short* __restrict__ Wb,
                                                   const float* __restrict__ bq,
                                                   const unsigned short* __restrict__ xt,
                                                   unsigned short* __restrict__ qb) {
    const int lt = blockIdx.x, h = blockIdx.y, b = blockIdx.z;
    const int tid = threadIdx.x, w = tid >> 6, lane = tid & 63;
    const int lr = lane & 15, lg = lane >> 4;
    const int l = lt * 64 + w * 16 + lr;
    const int o0 = h * 64;

    f32x4 acc[4] = {};
    const unsigned short* xrow = xt + ((size_t)b * L_ + l) * C_;
    for (int ks = 0; ks < 16; ++ks) {
        bf16x8 bf = *reinterpret_cast<const bf16x8*>(xrow + ks * 32 + lg * 8);
        #pragma unroll
        for (int mt = 0; mt < 4; ++mt) {
            bf16x8 af = *reinterpret_cast<const bf16x8*>(Wb + (size_t)(o0 + mt * 16 + lr) * C_ + ks * 32 + lg * 8);
            acc[mt] = __builtin_amdgcn_mfma_f32_16x16x32_bf16(af, bf, acc[mt], 0, 0, 0);
        }
    }
    const int bh = b * H_ + h;
    unsigned short* qrow = qb + ((size_t)bh * L_ + l) * 64;
    #pragma unroll
    for (int mt = 0; mt < 4; ++mt) {
        const int e0 = mt * 16 + lg * 4;
        const float4 bb = *reinterpret_cast<const float4*>(bq + o0 + e0);
        union { unsigned short u[4]; unsigned long long ll; } o;
        o.u[0] = f2bf((acc[mt][0] + bb.x) * QSCALE);
        o.u[1] = f2bf((acc[mt][1] + bb.y) * QSCALE);
        o.u[2] = f2bf((acc[mt][2] + bb.z) * QSCALE);
        o.u[3] = f2bf((acc[mt][3] + bb.w) * QSCALE);
        *reinterpret_cast<unsigned long long*>(qrow + e0) = o.ll;
    }
}

// ---------------- Pass C: fused S/softmax-sum/PV + residual + transposed write ----------------
// One PV phase: consume bank CUR, prefetch into bank NXT (next ks, or next k-tile's ks=0)
#define PV_PHASE(CUR, NXT, KS)                                                      \
    {                                                                               \
        const bool pf = ((KS) + 1 < ksmax) || (kt + 1 < nkt);                       \
        const int nl = ((KS) + 1 < ksmax) ? k0 + ((KS) + 1) * 32 : k0 + 128;        \
        if (pf) {                                                                   \
            _Pragma("unroll")                                                       \
            for (int ct = 0; ct < 4; ++ct)                                          \
                pvv[NXT][ct] = *reinterpret_cast<const bf16x8*>(                    \
                    Vbase + (size_t)(w * 64 + ct * 16 + lr) * L_ + nl + lg * 8);    \
        }                                                                           \
        bf16x8 pa[4];                                                               \
        _Pragma("unroll")                                                           \
        for (int mt = 0; mt < 4; ++mt) {                                            \
            const int row = mt * 16 + lr;                                           \
            const int g2 = ((KS) * 4 + lg) ^ lr;                                    \
            pa[mt] = *reinterpret_cast<const bf16x8*>(&Pb[row * 128 + (g2 << 3)]);  \
        }                                                                           \
        __builtin_amdgcn_s_setprio(1);                                              \
        _Pragma("unroll")                                                           \
        for (int mt = 0; mt < 4; ++mt)                                              \
            _Pragma("unroll")                                                       \
            for (int ct = 0; ct < 4; ++ct)                                          \
                acc[mt][ct] = __builtin_amdgcn_mfma_f32_16x16x32_bf16(              \
                    pa[mt], pvv[CUR][ct], acc[mt][ct], 0, 0, 0);                    \
        __builtin_amdgcn_s_setprio(0);                                              \
    }

__global__ __launch_bounds__(512, 3) void pv_kernel(const unsigned short* __restrict__ qb,
                                                    const unsigned short* __restrict__ xb,
                                                    const float* __restrict__ x,
                                                    float* __restrict__ out) {
    // XCD-locality swizzle: 512 blocks, hardware XCD = id%8; group so each XCD
    // serves exactly one b (V slab 2MB fits 4MB L2) and 4 heads.
    const int id = blockIdx.x;
    const int wid = (id & 7) * 64 + (id >> 3);
    const int b = wid >> 7, h = (wid >> 4) & 7, gx = wid & 15;
    const int tid = threadIdx.x, w = tid >> 6, lane = tid & 63;
    const int lr = lane & 15, lg = lane >> 4;
    const int bh = b * H_ + h;
    const unsigned short* Qbase = qb + (size_t)bh * L_ * 64;
    const unsigned short* Vbase = xb + (size_t)b * C_ * L_;
    const float* xres = x + (size_t)b * C_ * L_;
    float* ob = out + (size_t)bh * C_ * L_;

    __shared__ unsigned short Qt[64 * 64];       // swizzled Q tile
    __shared__ unsigned short P2[2][64 * 128];   // double-buffered P, XOR-swizzled
    __shared__ float rsT[64][8];                 // per-wave rowsum partials

    // two q-tiles per block: gx and 31-gx  => uniform 17 k-tile iters per block
    #pragma unroll 1
    for (int half = 0; half < 2; ++half) {
        const int qt = half ? (31 - gx) : gx;
        const int q0 = qt * 64, qlim = q0 + 63;
        const int nkt = (q0 >> 7) + 1;

        __syncthreads();   // previous half's readers of Qt/P2/rsT are done

        // stage Q tile into LDS (granule g -> g ^ (row&7))
        {
            const int r = tid >> 3, g = tid & 7;
            bf16x8 v = *reinterpret_cast<const bf16x8*>(Qbase + (size_t)(q0 + r) * 64 + g * 8);
            *reinterpret_cast<bf16x8*>(&Qt[r * 64 + ((g ^ (r & 7)) << 3)]) = v;
        }
        // preload K slab for k-tile 0
        bf16x8 kb0 = *reinterpret_cast<const bf16x8*>(Qbase + (size_t)(w * 16 + lr) * 64 + lg * 8);
        bf16x8 kb1 = *reinterpret_cast<const bf16x8*>(Qbase + (size_t)(w * 16 + lr) * 64 + 32 + lg * 8);
        // preload V bank A for (kt=0, ks=0)
        bf16x8 pvv[2][4];
        #pragma unroll
        for (int ct = 0; ct < 4; ++ct)
            pvv[0][ct] = *reinterpret_cast<const bf16x8*>(Vbase + (size_t)(w * 64 + ct * 16 + lr) * L_ + lg * 8);

        f32x4 acc[4][4] = {};
        float rs[4] = {0.f, 0.f, 0.f, 0.f};

        __syncthreads();   // Qt visible

        #pragma unroll 1
        for (int kt = 0; kt < nkt; ++kt) {
            const int k0 = kt * 128;
            const int ksmax = min(4, ((qlim - k0) >> 5) + 1);   // always 2 or 4
            unsigned short* Pb = (unsigned short*)P2[kt & 1];
            const bool active = (k0 + (w & ~1) * 16) <= qlim;

            if (active) {
                // S phase: z = K-slab x Q -> D[k][q], 4 consecutive k per lane
                f32x4 z[4];
                #pragma unroll
                for (int nt = 0; nt < 4; ++nt) {
                    bf16x8 aq0 = *reinterpret_cast<const bf16x8*>(&Qt[(nt * 16 + lr) * 64 + ((lg ^ (lr & 7)) << 3)]);
                    bf16x8 aq1 = *reinterpret_cast<const bf16x8*>(&Qt[(nt * 16 + lr) * 64 + (((4 + lg) ^ (lr & 7)) << 3)]);
                    f32x4 zz = {};
                    zz = __builtin_amdgcn_mfma_f32_16x16x32_bf16(kb0, aq0, zz, 0, 0, 0);
                    zz = __builtin_amdgcn_mfma_f32_16x16x32_bf16(kb1, aq1, zz, 0, 0, 0);
                    z[nt] = zz;
                }
                if (kt + 1 < nkt) {   // prefetch next K slab under the exp tail
                    const size_t krow = (size_t)(k0 + 128 + w * 16 + lr) * 64;
                    kb0 = *reinterpret_cast<const bf16x8*>(Qbase + krow + lg * 8);
                    kb1 = *reinterpret_cast<const bf16x8*>(Qbase + krow + 32 + lg * 8);
                }
                const int kbase = k0 + w * 16 + lg * 4;
                #pragma unroll
                for (int nt = 0; nt < 4; ++nt) {
                    const int q = q0 + nt * 16 + lr;
                    const float p0 = (kbase + 0 <= q) ? exp2f(z[nt][0]) : 0.f;
                    const float p1 = (kbase + 1 <= q) ? exp2f(z[nt][1]) : 0.f;
                    const float p2 = (kbase + 2 <= q) ? exp2f(z[nt][2]) : 0.f;
                    const float p3 = (kbase + 3 <= q) ? exp2f(z[nt][3]) : 0.f;
                    rs[nt] += (p0 + p1) + (p2 + p3);
                    unsigned r01, r23;
                    asm("v_cvt_pk_bf16_f32 %0, %1, %2" : "=v"(r01) : "v"(p0), "v"(p1));
                    asm("v_cvt_pk_bf16_f32 %0, %1, %2" : "=v"(r23) : "v"(p2), "v"(p3));
                    const int row = nt * 16 + lr;
                    const int col = w * 16 + lg * 4;
                    const int gg = (col >> 3) ^ lr;
                    const unsigned long long pk = ((unsigned long long)r23 << 32) | r01;
                    *reinterpret_cast<unsigned long long*>(&Pb[row * 128 + (gg << 3) + (col & 7)]) = pk;
                }
            } else if (kt + 1 < nkt) {
                const size_t krow = (size_t)(k0 + 128 + w * 16 + lr) * 64;
                kb0 = *reinterpret_cast<const bf16x8*>(Qbase + krow + lg * 8);
                kb1 = *reinterpret_cast<const bf16x8*>(Qbase + krow + 32 + lg * 8);
            }
            __syncthreads();   // P ready; V-bank-A loads issued last iter are drained here
                               // (covered by the S phase above)

            // PV: wave owns channels [w*64, w*64+64); 2-bank register pipeline on V
            PV_PHASE(0, 1, 0)
            PV_PHASE(1, 0, 1)
            if (ksmax == 4) {
                PV_PHASE(0, 1, 2)
                PV_PHASE(1, 0, 3)
            }
        }

        // rowsum: lane-local partials -> reduce across lg groups -> LDS merge across waves
        #pragma unroll
        for (int nt = 0; nt < 4; ++nt) {
            float t0 = __shfl_xor(rs[nt], 16); rs[nt] += t0;
            float t1 = __shfl_xor(rs[nt], 32); rs[nt] += t1;
        }
        if (lg == 0) {
            #pragma unroll
            for (int nt = 0; nt < 4; ++nt) rsT[nt * 16 + lr][w] = rs[nt];
        }
        __syncthreads();
        float li[16];
        #pragma unroll
        for (int mt = 0; mt < 4; ++mt)
            #pragma unroll
            for (int r = 0; r < 4; ++r) {
                const int row = mt * 16 + lg * 4 + r;
                const f32x4 s0 = *reinterpret_cast<const f32x4*>(&rsT[row][0]);
                const f32x4 s1 = *reinterpret_cast<const f32x4*>(&rsT[row][4]);
                li[mt * 4 + r] = 1.f / (((s0[0] + s0[1]) + (s0[2] + s0[3])) + ((s1[0] + s1[1]) + (s1[2] + s1[3])));
            }

        #pragma unroll
        for (int mt = 0; mt < 4; ++mt) {
            const int lbase = q0 + mt * 16 + lg * 4;
            #pragma unroll
            for (int ct = 0; ct < 4; ++ct) {
                const int c = w * 64 + ct * 16 + lr;
                const f32x4 res = *reinterpret_cast<const f32x4*>(xres + (size_t)c * L_ + lbase);
                f32x4 o;
                #pragma unroll
                for (int r = 0; r < 4; ++r) o[r] = acc[mt][ct][r] * li[mt * 4 + r] + res[r];
                *reinterpret_cast<f32x4*>(ob + (size_t)c * L_ + lbase) = o;
            }
        }
    }
}

extern "C" void kernel_launch(void* const* d_in, const int* in_sizes, int n_in,
                              void* d_out, int out_size, void* d_ws, size_t ws_size,
                              hipStream_t stream) {
    const float* x  = (const float*)d_in[0];
    const float* Wq = (const float*)d_in[1];
    const float* bq = (const float*)d_in[2];
    float* out = (float*)d_out;

    unsigned short* xb   = (unsigned short*)d_ws;                        // B*C*L bf16   = 8 MiB
    unsigned short* xt   = xb + (size_t)B_ * C_ * L_;                    // B*L*C bf16   = 8 MiB
    unsigned short* qbuf = xt + (size_t)B_ * L_ * C_;                    // B*H*L*E bf16 = 8 MiB
    unsigned short* Wb   = qbuf + (size_t)B_ * H_ * L_ * E_;             // 512 KiB

    prep_kernel<<<dim3(32, 8, 4), 256, 0, stream>>>(x, xb, xt);
    wcast_kernel<<<dim3(256), 256, 0, stream>>>(Wq, Wb);
    proj_kernel<<<dim3(32, 8, 4), 256, 0, stream>>>(Wb, bq, xt, qbuf);
    pv_kernel<<<dim3(512), 512, 0, stream>>>(qbuf, xb, x, out);
}